// Round 8
// baseline (351.738 us; speedup 1.0000x reference)
//
#include <hip/hip_runtime.h>

// ---------- types ----------
typedef __attribute__((ext_vector_type(8))) short short8;
typedef __attribute__((ext_vector_type(4))) float f32x4;
typedef __attribute__((ext_vector_type(4))) float float4v;
typedef __attribute__((ext_vector_type(4))) unsigned short us4;

__device__ __forceinline__ unsigned short f2bf(float f) {
  union { float f; unsigned int u; } c; c.f = f;
  unsigned int u = c.u;
  u += 0x7fffu + ((u >> 16) & 1u);
  return (unsigned short)(u >> 16);
}

__device__ __forceinline__ unsigned int pkbf(float a, float b) {
  unsigned int r;
  asm("v_cvt_pk_bf16_f32 %0, %1, %2" : "=v"(r) : "v"(a), "v"(b));
  return r;
}

// 2^x via compiler-known TRANS op (hazard nops handled by backend).
__device__ __forceinline__ float exp2r(float x) {
#if __has_builtin(__builtin_amdgcn_exp2f)
  return __builtin_amdgcn_exp2f(x);
#else
  return exp2f(x);
#endif
}

__device__ __forceinline__ void async16(const void* g, void* l) {
  __builtin_amdgcn_global_load_lds(
      (const __attribute__((address_space(1))) unsigned int*)g,
      (__attribute__((address_space(3))) unsigned int*)l, 16, 0, 0);
}

__device__ __forceinline__ f32x4 mfma16(short8 a, short8 b, f32x4 c) {
  return __builtin_amdgcn_mfma_f32_16x16x32_bf16(a, b, c, 0, 0, 0);
}

// ---------- fused fp32 -> bf16 cast, reordered for fused GEMMs ----------
__global__ void cast_all(const float* __restrict__ x,
                         const float* __restrict__ wqa, const float* __restrict__ wqb,
                         const float* __restrict__ wka, const float* __restrict__ wkb,
                         const float* __restrict__ wva, const float* __restrict__ wvb,
                         const float* __restrict__ wow,
                         unsigned short* __restrict__ out) {
  int c = blockIdx.x * 256 + threadIdx.x;
  const int stride = gridDim.x * 256;
  for (; c < 4718592; c += stride) {
    int i = c << 2;
    const float* src; int off;
    if (i < 8388608)       { src = x;   off = 0; }
    else if (i < 9437184)  { src = wqa; off = 8388608; }
    else if (i < 10485760) { src = wka; off = 9437184; }
    else if (i < 11534336) { src = wva; off = 10485760; }
    else if (i < 12582912) { src = wqb; off = 11534336; }
    else if (i < 13631488) { src = wkb; off = 12582912; }
    else if (i < 14680064) { src = wvb; off = 13631488; }
    else                   { src = wow; off = 14680064; }
    float4v v = *(const float4v*)(src + (i - off));
    us4 r;
    r[0] = f2bf(v[0]); r[1] = f2bf(v[1]); r[2] = f2bf(v[2]); r[3] = f2bf(v[3]);
    *(us4*)(out + i) = r;
  }
}

// ---------- GEMM epilogue (shared) ----------
// modes: 0 bf16 | 1 bf16 v^T+key-perm | 2 fp32+bias | 3 bf16*qscale
template <int NT>
__device__ __forceinline__ void gemm_epilogue(
    f32x4 (&acc)[4][NT], void* __restrict__ Cv, int ldc,
    const float* __restrict__ bias, float qscale, int mode,
    int tile_m, int tile_n, int wm, int wn, int lr, int lg) {
#pragma unroll
  for (int mt = 0; mt < 4; mt++) {
#pragma unroll
    for (int nt = 0; nt < NT; nt++) {
#pragma unroll
      for (int r = 0; r < 4; r++) {
        int row = tile_m + wm + mt * 16 + lg * 4 + r;
        int col = tile_n + wn + nt * 16 + lr;
        float v = acc[mt][nt][r];
        if (mode == 0) {
          ((unsigned short*)Cv)[(size_t)row * ldc + col] = f2bf(v);
        } else if (mode == 3) {
          ((unsigned short*)Cv)[(size_t)row * ldc + col] = f2bf(v * qscale);
        } else if (mode == 1) {
          int tl = row & 2047;
          int key = tl & 63;
          int tp = (tl & ~63) | ((key & 15) << 2) | (key >> 4);
          ((unsigned short*)Cv)[((size_t)((row >> 11) << 11) + col) * 2048 + tp] = f2bf(v);
        } else {
          ((float*)Cv)[(size_t)row * ldc + col] = v + bias[col];
        }
      }
    }
  }
}

// ---------- GEMM body, counted-vmcnt pipeline (T4, validated R6) ----------
// Prefetch for step s+1 stays IN FLIGHT across the barriers: issue batch
// (s+1) -> s_waitcnt vmcnt(6) (waits only batch s; never 0 in-loop) ->
// raw barrier -> compute(s) -> raw barrier. Latency window = one full step.
// R6 A/B on out-proj: -8us vs drain body. R7: BN=128 variant (2 blocks/CU)
// was ~4us WORSE than BN=64 (3 blocks/CU) -> cnt64 is the validated config.
template <int BN>
__device__ __forceinline__ void gemm_body_cnt(
    const unsigned short* __restrict__ A, int lda,
    const unsigned short* __restrict__ B, int ldb,
    void* __restrict__ Cv, int ldc,
    const float* __restrict__ bias, float qscale, int K, int mode) {
  constexpr int NT = BN / 32;
  __shared__ __align__(16) unsigned short As[2][128 * 64];
  __shared__ __align__(16) unsigned short Bs[2][BN * 64];
  const int tid  = threadIdx.x;
  const int wave = tid >> 6, lane = tid & 63;
  const int lr = lane & 15, lg = lane >> 4;
  const int lr7 = lr & 7;
  const int tile_m = blockIdx.y << 7;
  const int tile_n = blockIdx.x * BN;
  const int wm = (wave & 1) << 6;
  const int wn = (wave >> 1) * (BN / 2);

  f32x4 acc[4][NT];
#pragma unroll
  for (int i = 0; i < 4; i++)
#pragma unroll
    for (int j = 0; j < NT; j++) acc[i][j] = (f32x4)0.0f;

  const int srow = tid >> 3;
  const int cg = ((tid & 7) ^ (srow & 7)) << 3;
  const unsigned short* Ag = A + (size_t)(tile_m + srow) * lda + cg;
  const unsigned short* Bg = B + (size_t)(tile_n + srow) * ldb + cg;
  const size_t rowskipA = (size_t)32 * lda;
  const size_t rowskipB = (size_t)32 * ldb;
  const int woff = wave * 512;

  // prologue: issue batch(0) into buf 0 (stays in flight; waited in s=0)
#pragma unroll
  for (int i = 0; i < 4; i++)
    async16(Ag + i * rowskipA, &As[0][woff + i * 2048]);
#pragma unroll
  for (int i = 0; i < BN / 32; i++)
    async16(Bg + i * rowskipB, &Bs[0][woff + i * 2048]);

  const int nsteps = K >> 6;
  for (int s = 0; s < nsteps; ++s) {
    const int cur = s & 1;
    if (s + 1 < nsteps) {
      const int k0 = (s + 1) << 6;
      // issue batch(s+1) into buf cur^1 (read-clear by barrier #2 of s-1)
#pragma unroll
      for (int i = 0; i < 4; i++)
        async16(Ag + k0 + i * rowskipA, &As[cur ^ 1][woff + i * 2048]);
#pragma unroll
      for (int i = 0; i < BN / 32; i++)
        async16(Bg + k0 + i * rowskipB, &Bs[cur ^ 1][woff + i * 2048]);
      // wait batch(s) only; batch(s+1) (4+NT loads) stays outstanding
      asm volatile("s_waitcnt vmcnt(6)" ::: "memory");
    } else {
      asm volatile("s_waitcnt vmcnt(0)" ::: "memory");
    }
    __builtin_amdgcn_s_barrier();  // all waves' batch(s) landed in LDS
#pragma unroll
    for (int kk = 0; kk < 2; kk++) {
      short8 af[4], bf[NT];
#pragma unroll
      for (int mt = 0; mt < 4; mt++)
        af[mt] = *(const short8*)&As[cur][(wm + mt * 16 + lr) * 64 + (((kk * 4 + lg) ^ lr7) << 3)];
#pragma unroll
      for (int nt = 0; nt < NT; nt++)
        bf[nt] = *(const short8*)&Bs[cur][(wn + nt * 16 + lr) * 64 + (((kk * 4 + lg) ^ lr7) << 3)];
#pragma unroll
      for (int mt = 0; mt < 4; mt++)
#pragma unroll
        for (int nt = 0; nt < NT; nt++)
          acc[mt][nt] = mfma16(af[mt], bf[nt], acc[mt][nt]);
    }
    __builtin_amdgcn_s_barrier();  // readers of buf cur done before s+1's overwrite
  }
  gemm_epilogue<NT>(acc, Cv, ldc, bias, qscale, mode, tile_m, tile_n, wm, wn, lr, lg);
}

// down-projection: [4096,2048] x [1536,2048]^T -> [4096,1536] bf16.
// counted body BN=64: LDS 48KB -> 3 blocks/CU, grid 768 = exactly 3/CU.
__global__ __launch_bounds__(256)
void gemm_dn(const unsigned short* __restrict__ A,
             const unsigned short* __restrict__ B,
             unsigned short* __restrict__ C) {
  gemm_body_cnt<64>(A, 2048, B, 2048, C, 1536, nullptr, 1.0f, 2048, 0);
}

// output projection + bias -> fp32: counted body BN=64 (R6-validated;
// R7's BN=128 at 2 blocks/CU was ~4us slower -> reverted).
__global__ __launch_bounds__(256)
void gemm_out(const unsigned short* __restrict__ A,
              const unsigned short* __restrict__ B,
              float* __restrict__ C, const float* __restrict__ bias) {
  gemm_body_cnt<64>(A, 2048, B, 2048, C, 2048, bias, 1.0f, 2048, 2);
}

// batched up-projection: z=0 -> Q (scaled), z=1 -> K, z=2 -> V^T permuted.
// Last drain-body GEMM converted to the validated cnt64 pipeline: K=512
// (8 steps), grid 32x32x3 = 3072 blocks, 48KB LDS -> 3 resident/CU with a
// deep queue (rotating blocks overlap epilogue/prologue).
__global__ __launch_bounds__(256)
void gemm_up(const unsigned short* __restrict__ cdown,
             const unsigned short* __restrict__ wup,
             unsigned short* __restrict__ qb,
             unsigned short* __restrict__ kb,
             unsigned short* __restrict__ vtb) {
  const int z = blockIdx.z;
  const unsigned short* A = cdown + z * 512;
  const unsigned short* B = wup + (size_t)z * 1048576;
  void* C; int mode; float qs = 1.0f;
  if (z == 0)      { C = qb;  mode = 3; qs = 0.12751744f; }  // (1/sqrt(128))*log2(e)
  else if (z == 1) { C = kb;  mode = 0; }
  else             { C = vtb; mode = 1; }
  gemm_body_cnt<64>(A, 1536, B, 512, C, 2048, nullptr, qs, 512, mode);
}

// ---------- flash attention (unshifted softmax, log2 domain) ----------
// 512 threads / 8 waves / 128 q-rows per block; 16 q-rows per wave.
// 2-tile pipeline: QK^T(t+1) and PV(t) issue back-to-back; P fragments in
// registers across the barrier. 74us = 924 TF (plain-HIP ladder level).
__global__ __launch_bounds__(512)
void attn(const unsigned short* __restrict__ q,
          const unsigned short* __restrict__ k,
          const unsigned short* __restrict__ vt,
          unsigned short* __restrict__ o) {
  __shared__ __align__(16) unsigned short Ks[2][64 * 128];
  __shared__ __align__(16) unsigned short Vs[2][128 * 64];
  __shared__ __align__(16) unsigned short Ps[8][16 * 64];

  const int tid  = threadIdx.x;
  const int wave = tid >> 6, lane = tid & 63;
  const int lr = lane & 15, lg = lane >> 4;
  // bijective XCD swizzle over 512 blocks: each XCD owns 4 bh x 16 q-tiles
  const int lin = blockIdx.x + (blockIdx.y << 4);
  const int xcd = lin & 7;
  const int lcl = lin >> 3;
  const int bh = (xcd << 2) | (lcl & 3);
  const int b = bh >> 4, h = bh & 15;
  const int q0 = (lcl >> 2) << 7;

  const size_t qrow = (size_t)(b * 2048 + q0 + wave * 16 + lr);
  short8 qf[4];
#pragma unroll
  for (int kk = 0; kk < 4; kk++)
    qf[kk] = *(const short8*)(q + qrow * 2048 + h * 128 + kk * 32 + lg * 8);

  f32x4 oacc[8];
  f32x4 lacc = (f32x4)0.0f;
#pragma unroll
  for (int n2 = 0; n2 < 8; n2++) oacc[n2] = (f32x4)0.0f;

  short8 ones;
#pragma unroll
  for (int j = 0; j < 8; j++) ones[j] = (short)0x3F80;  // bf16 1.0

  const unsigned short* kg = k  + (size_t)(b * 2048 + (tid >> 4)) * 2048 + h * 128
                               + ((((tid & 15) ^ (tid >> 4)) & 15) << 3);
  const unsigned short* vg = vt + (size_t)(bh * 128 + (tid >> 3)) * 2048
                               + (((tid & 7) ^ ((tid >> 3) & 7)) << 3);
  const int lr7 = lr & 7;

  // prologue staging: K(0)->Ks[0], V(0)->Vs[0], K(1)->Ks[1]
#pragma unroll
  for (int i = 0; i < 2; i++) {
    async16(kg + (size_t)(i * 32) * 2048, &Ks[0][i * 4096 + wave * 512]);
    async16(vg + (size_t)(i * 64) * 2048, &Vs[0][i * 4096 + wave * 512]);
    async16(kg + (size_t)(64 + i * 32) * 2048, &Ks[1][i * 4096 + wave * 512]);
  }
  __syncthreads();  // vmcnt(0): K0,V0,K1 resident

  short8 pfA, pfB;
  {
    // QK^T(0)
    f32x4 sv[4];
#pragma unroll
    for (int nt = 0; nt < 4; nt++) sv[nt] = (f32x4)0.0f;
#pragma unroll
    for (int nt = 0; nt < 4; nt++) {
#pragma unroll
      for (int kk = 0; kk < 4; kk++) {
        short8 kf = *(const short8*)&Ks[0][(nt * 16 + lr) * 128 + (((kk * 4 + lg) ^ lr) << 3)];
        sv[nt] = mfma16(qf[kk], kf, sv[nt]);
      }
    }
    // exp(0) -> Ps -> pf regs
#pragma unroll
    for (int r = 0; r < 4; r++) {
      float p0 = exp2r(sv[0][r]);
      float p1 = exp2r(sv[1][r]);
      float p2 = exp2r(sv[2][r]);
      float p3 = exp2r(sv[3][r]);
      uint2 pk; pk.x = pkbf(p0, p1); pk.y = pkbf(p2, p3);
      int row = lg * 4 + r;
      *(uint2*)&Ps[wave][row * 64 + ((lr ^ (lg << 2)) << 2)] = pk;
    }
    pfA = *(const short8*)&Ps[wave][lr * 64 + (((lg * 2) ^ ((lr >> 2) << 2)) << 2)];
    pfB = *(const short8*)&Ps[wave][lr * 64 + (((8 + lg * 2) ^ ((lr >> 2) << 2)) << 2)];
  }
  __syncthreads();  // all waves done reading Ks[0] before iter0 overwrites it

  for (int t = 0; t < 31; ++t) {
    const int buf = t & 1;
    // stage K(t+2) into Ks[buf] (last read by QKT(t) in iter t-1)
    if (t < 30) {
#pragma unroll
      for (int i = 0; i < 2; i++)
        async16(kg + (size_t)((t + 2) * 64 + i * 32) * 2048, &Ks[buf][i * 4096 + wave * 512]);
    }
    // stage V(t+1) into Vs[buf^1] (last read by PV(t-1) in iter t-1)
#pragma unroll
    for (int i = 0; i < 2; i++)
      async16(vg + (t + 1) * 64 + (size_t)(i * 64) * 2048, &Vs[buf ^ 1][i * 4096 + wave * 512]);

    const unsigned short* KsN = Ks[buf ^ 1];
    const unsigned short* VsB = Vs[buf];

    __builtin_amdgcn_s_setprio(1);
    // QK^T(t+1) — independent of PV(t)
    f32x4 sv[4];
#pragma unroll
    for (int nt = 0; nt < 4; nt++) sv[nt] = (f32x4)0.0f;
#pragma unroll
    for (int nt = 0; nt < 4; nt++) {
#pragma unroll
      for (int kk = 0; kk < 4; kk++) {
        short8 kf = *(const short8*)&KsN[(nt * 16 + lr) * 128 + (((kk * 4 + lg) ^ lr) << 3)];
        sv[nt] = mfma16(qf[kk], kf, sv[nt]);
      }
    }

    // PV(t) from register-held P fragments + Vs[buf]
    lacc = mfma16(pfA, ones, lacc);
#pragma unroll
    for (int n2 = 0; n2 < 8; n2++) {
      short8 vf = *(const short8*)&VsB[(n2 * 16 + lr) * 64 + ((lg ^ lr7) << 3)];
      oacc[n2] = mfma16(pfA, vf, oacc[n2]);
    }
    lacc = mfma16(pfB, ones, lacc);
#pragma unroll
    for (int n2 = 0; n2 < 8; n2++) {
      short8 vf = *(const short8*)&VsB[(n2 * 16 + lr) * 64 + (((4 + lg) ^ lr7) << 3)];
      oacc[n2] = mfma16(pfB, vf, oacc[n2]);
    }
    __builtin_amdgcn_s_setprio(0);

    // exp(t+1) -> Ps -> pf regs
#pragma unroll
    for (int r = 0; r < 4; r++) {
      float p0 = exp2r(sv[0][r]);
      float p1 = exp2r(sv[1][r]);
      float p2 = exp2r(sv[2][r]);
      float p3 = exp2r(sv[3][r]);
      uint2 pk; pk.x = pkbf(p0, p1); pk.y = pkbf(p2, p3);
      int row = lg * 4 + r;
      *(uint2*)&Ps[wave][row * 64 + ((lr ^ (lg << 2)) << 2)] = pk;
    }
    pfA = *(const short8*)&Ps[wave][lr * 64 + (((lg * 2) ^ ((lr >> 2) << 2)) << 2)];
    pfB = *(const short8*)&Ps[wave][lr * 64 + (((8 + lg * 2) ^ ((lr >> 2) << 2)) << 2)];

    __syncthreads();
  }

  // final PV(31) from Vs[1]
  {
    const unsigned short* VsB = Vs[1];
    __builtin_amdgcn_s_setprio(1);
    lacc = mfma16(pfA, ones, lacc);
#pragma unroll
    for (int n2 = 0; n2 < 8; n2++) {
      short8 vf = *(const short8*)&VsB[(n2 * 16 + lr) * 64 + ((lg ^ lr7) << 3)];
      oacc[n2] = mfma16(pfA, vf, oacc[n2]);
    }
    lacc = mfma16(pfB, ones, lacc);
#pragma unroll
    for (int n2 = 0; n2 < 8; n2++) {
      short8 vf = *(const short8*)&VsB[(n2 * 16 + lr) * 64 + (((4 + lg) ^ lr7) << 3)];
      oacc[n2] = mfma16(pfB, vf, oacc[n2]);
    }
    __builtin_amdgcn_s_setprio(0);
  }

  // epilogue: l in C-layout aligned with oacc rows
  f32x4 inv;
#pragma unroll
  for (int r = 0; r < 4; r++) inv[r] = 1.0f / lacc[r];
#pragma unroll
  for (int n2 = 0; n2 < 8; n2++)
#pragma unroll
    for (int r = 0; r < 4; r++) {
      size_t row = (size_t)(b * 2048 + q0 + wave * 16 + lg * 4 + r);
      o[row * 2048 + h * 128 + n2 * 16 + lr] = f2bf(oacc[n2][r] * inv[r]);
    }
}

// ---------- host ----------
extern "C" void kernel_launch(void* const* d_in, const int* in_sizes, int n_in,
                              void* d_out, int out_size, void* d_ws, size_t ws_size,
                              hipStream_t stream) {
  const float* x    = (const float*)d_in[0];
  const float* wq_a = (const float*)d_in[1];
  const float* wq_b = (const float*)d_in[2];
  const float* wk_a = (const float*)d_in[3];
  const float* wk_b = (const float*)d_in[4];
  const float* wv_a = (const float*)d_in[5];
  const float* wv_b = (const float*)d_in[6];
  const float* wo_w = (const float*)d_in[7];
  const float* wo_b = (const float*)d_in[8];
  float* out = (float*)d_out;

  unsigned short* ws = (unsigned short*)d_ws;
  unsigned short* xb    = ws;
  unsigned short* wdown = ws + 8388608;    // [1536][2048]
  unsigned short* wupb  = ws + 11534336;   // [3][2048][512]
  unsigned short* wow   = ws + 14680064;   // [2048][2048]
  unsigned short* cdown = ws + 18874368;   // [4096][1536]
  unsigned short* qb    = ws + 25165824;   // [4096][2048]
  unsigned short* kb    = ws + 33554432;
  unsigned short* vtb   = ws + 41943040;
  unsigned short* ao    = ws + 50331648;

  cast_all<<<dim3(2048), dim3(256), 0, stream>>>(x, wq_a, wq_b, wk_a, wk_b, wv_a, wv_b, wo_w, ws);

  // fused down-projection: [4096,2048] x [1536,2048]^T -> [4096,1536]
  gemm_dn<<<dim3(24, 32), dim3(256), 0, stream>>>(xb, wdown, cdown);

  // batched up-projections (Q scaled, K plain, V transposed+permuted)
  gemm_up<<<dim3(32, 32, 3), dim3(256), 0, stream>>>(cdown, wupb, qb, kb, vtb);

  attn<<<dim3(16, 32), dim3(512), 0, stream>>>(qb, kb, vtb, ao);

  // output projection + bias -> fp32 (counted-vmcnt BN=64, R6-validated)
  gemm_out<<<dim3(32, 32), dim3(256), 0, stream>>>(ao, wow, out, wo_b);
}

// Round 9
// 335.169 us; speedup vs baseline: 1.0494x; 1.0494x over previous
//
#include <hip/hip_runtime.h>

// ---------- types ----------
typedef __attribute__((ext_vector_type(8))) short short8;
typedef __attribute__((ext_vector_type(4))) float f32x4;
typedef __attribute__((ext_vector_type(4))) float float4v;
typedef __attribute__((ext_vector_type(4))) unsigned short us4;

__device__ __forceinline__ unsigned short f2bf(float f) {
  union { float f; unsigned int u; } c; c.f = f;
  unsigned int u = c.u;
  u += 0x7fffu + ((u >> 16) & 1u);
  return (unsigned short)(u >> 16);
}

__device__ __forceinline__ unsigned int pkbf(float a, float b) {
  unsigned int r;
  asm("v_cvt_pk_bf16_f32 %0, %1, %2" : "=v"(r) : "v"(a), "v"(b));
  return r;
}

// 2^x via compiler-known TRANS op (hazard nops handled by backend).
__device__ __forceinline__ float exp2r(float x) {
#if __has_builtin(__builtin_amdgcn_exp2f)
  return __builtin_amdgcn_exp2f(x);
#else
  return exp2f(x);
#endif
}

__device__ __forceinline__ void async16(const void* g, void* l) {
  __builtin_amdgcn_global_load_lds(
      (const __attribute__((address_space(1))) unsigned int*)g,
      (__attribute__((address_space(3))) unsigned int*)l, 16, 0, 0);
}

__device__ __forceinline__ f32x4 mfma16(short8 a, short8 b, f32x4 c) {
  return __builtin_amdgcn_mfma_f32_16x16x32_bf16(a, b, c, 0, 0, 0);
}

// ---------- fused fp32 -> bf16 cast, reordered for fused GEMMs ----------
__global__ void cast_all(const float* __restrict__ x,
                         const float* __restrict__ wqa, const float* __restrict__ wqb,
                         const float* __restrict__ wka, const float* __restrict__ wkb,
                         const float* __restrict__ wva, const float* __restrict__ wvb,
                         const float* __restrict__ wow,
                         unsigned short* __restrict__ out) {
  int c = blockIdx.x * 256 + threadIdx.x;
  const int stride = gridDim.x * 256;
  for (; c < 4718592; c += stride) {
    int i = c << 2;
    const float* src; int off;
    if (i < 8388608)       { src = x;   off = 0; }
    else if (i < 9437184)  { src = wqa; off = 8388608; }
    else if (i < 10485760) { src = wka; off = 9437184; }
    else if (i < 11534336) { src = wva; off = 10485760; }
    else if (i < 12582912) { src = wqb; off = 11534336; }
    else if (i < 13631488) { src = wkb; off = 12582912; }
    else if (i < 14680064) { src = wvb; off = 13631488; }
    else                   { src = wow; off = 14680064; }
    float4v v = *(const float4v*)(src + (i - off));
    us4 r;
    r[0] = f2bf(v[0]); r[1] = f2bf(v[1]); r[2] = f2bf(v[2]); r[3] = f2bf(v[3]);
    *(us4*)(out + i) = r;
  }
}

// ---------- GEMM epilogue (shared) ----------
// modes: 0 bf16 | 1 bf16 v^T+key-perm | 2 fp32+bias | 3 bf16*qscale
template <int NT>
__device__ __forceinline__ void gemm_epilogue(
    f32x4 (&acc)[4][NT], void* __restrict__ Cv, int ldc,
    const float* __restrict__ bias, float qscale, int mode,
    int tile_m, int tile_n, int wm, int wn, int lr, int lg) {
#pragma unroll
  for (int mt = 0; mt < 4; mt++) {
#pragma unroll
    for (int nt = 0; nt < NT; nt++) {
#pragma unroll
      for (int r = 0; r < 4; r++) {
        int row = tile_m + wm + mt * 16 + lg * 4 + r;
        int col = tile_n + wn + nt * 16 + lr;
        float v = acc[mt][nt][r];
        if (mode == 0) {
          ((unsigned short*)Cv)[(size_t)row * ldc + col] = f2bf(v);
        } else if (mode == 3) {
          ((unsigned short*)Cv)[(size_t)row * ldc + col] = f2bf(v * qscale);
        } else if (mode == 1) {
          int tl = row & 2047;
          int key = tl & 63;
          int tp = (tl & ~63) | ((key & 15) << 2) | (key >> 4);
          ((unsigned short*)Cv)[((size_t)((row >> 11) << 11) + col) * 2048 + tp] = f2bf(v);
        } else {
          ((float*)Cv)[(size_t)row * ldc + col] = v + bias[col];
        }
      }
    }
  }
}

// ---------- GEMM body (2-barrier, single-buffer drain) — gemm_up only ----
// For short-K / occupancy-rich shapes (K=512, 24KB LDS -> 5+ blocks/CU):
// wave-level TLP already hides staging latency (m114 regime); R8 showed
// the counted pipeline REGRESSES here (+20us: 8 steps amortize poorly,
// BN=64 doubles A-traffic, LDS 48KB cuts occupancy).
template <int BN>
__device__ __forceinline__ void gemm_body(
    const unsigned short* __restrict__ A, int lda,
    const unsigned short* __restrict__ B, int ldb,
    void* __restrict__ Cv, int ldc,
    const float* __restrict__ bias, float qscale, int K, int mode) {
  constexpr int NT = BN / 32;
  __shared__ __align__(16) unsigned short As[128 * 64];
  __shared__ __align__(16) unsigned short Bs[BN * 64];
  const int tid  = threadIdx.x;
  const int wave = tid >> 6, lane = tid & 63;
  const int lr = lane & 15, lg = lane >> 4;
  const int lr7 = lr & 7;
  const int tile_m = blockIdx.y << 7;
  const int tile_n = blockIdx.x * BN;
  const int wm = (wave & 1) << 6;
  const int wn = (wave >> 1) * (BN / 2);

  f32x4 acc[4][NT];
#pragma unroll
  for (int i = 0; i < 4; i++)
#pragma unroll
    for (int j = 0; j < NT; j++) acc[i][j] = (f32x4)0.0f;

  const int srow = tid >> 3;
  const int cg = ((tid & 7) ^ (srow & 7)) << 3;
  const unsigned short* Ag = A + (size_t)(tile_m + srow) * lda + cg;
  const unsigned short* Bg = B + (size_t)(tile_n + srow) * ldb + cg;
  const size_t rowskipA = (size_t)32 * lda;
  const size_t rowskipB = (size_t)32 * ldb;
  unsigned short* AsW = As + wave * 512;
  unsigned short* BsW = Bs + wave * 512;

  for (int k0 = 0; k0 < K; k0 += 64) {
#pragma unroll
    for (int i = 0; i < 4; i++)
      async16(Ag + k0 + i * rowskipA, AsW + i * 2048);
#pragma unroll
    for (int i = 0; i < BN / 32; i++)
      async16(Bg + k0 + i * rowskipB, BsW + i * 2048);
    __syncthreads();
#pragma unroll
    for (int kk = 0; kk < 2; kk++) {
      short8 af[4], bf[NT];
#pragma unroll
      for (int mt = 0; mt < 4; mt++)
        af[mt] = *(const short8*)&As[(wm + mt * 16 + lr) * 64 + (((kk * 4 + lg) ^ lr7) << 3)];
#pragma unroll
      for (int nt = 0; nt < NT; nt++)
        bf[nt] = *(const short8*)&Bs[(wn + nt * 16 + lr) * 64 + (((kk * 4 + lg) ^ lr7) << 3)];
#pragma unroll
      for (int mt = 0; mt < 4; mt++)
#pragma unroll
        for (int nt = 0; nt < NT; nt++)
          acc[mt][nt] = mfma16(af[mt], bf[nt], acc[mt][nt]);
    }
    __syncthreads();
  }
  gemm_epilogue<NT>(acc, Cv, ldc, bias, qscale, mode, tile_m, tile_n, wm, wn, lr, lg);
}

// ---------- GEMM body, counted-vmcnt pipeline (T4, validated R6) ----------
// For long-K / occupancy-thin shapes (K=2048, 2-3 blocks/CU): prefetch for
// step s+1 stays IN FLIGHT across the barriers: issue batch(s+1) ->
// s_waitcnt vmcnt(6) (waits only batch s; never 0 in-loop) -> raw barrier
// -> compute(s) -> raw barrier. R6 A/B: -8us vs drain on out-proj.
// R7: BN=128 (2 blocks/CU) ~4us worse than BN=64 -> cnt64 is the config.
template <int BN>
__device__ __forceinline__ void gemm_body_cnt(
    const unsigned short* __restrict__ A, int lda,
    const unsigned short* __restrict__ B, int ldb,
    void* __restrict__ Cv, int ldc,
    const float* __restrict__ bias, float qscale, int K, int mode) {
  constexpr int NT = BN / 32;
  __shared__ __align__(16) unsigned short As[2][128 * 64];
  __shared__ __align__(16) unsigned short Bs[2][BN * 64];
  const int tid  = threadIdx.x;
  const int wave = tid >> 6, lane = tid & 63;
  const int lr = lane & 15, lg = lane >> 4;
  const int lr7 = lr & 7;
  const int tile_m = blockIdx.y << 7;
  const int tile_n = blockIdx.x * BN;
  const int wm = (wave & 1) << 6;
  const int wn = (wave >> 1) * (BN / 2);

  f32x4 acc[4][NT];
#pragma unroll
  for (int i = 0; i < 4; i++)
#pragma unroll
    for (int j = 0; j < NT; j++) acc[i][j] = (f32x4)0.0f;

  const int srow = tid >> 3;
  const int cg = ((tid & 7) ^ (srow & 7)) << 3;
  const unsigned short* Ag = A + (size_t)(tile_m + srow) * lda + cg;
  const unsigned short* Bg = B + (size_t)(tile_n + srow) * ldb + cg;
  const size_t rowskipA = (size_t)32 * lda;
  const size_t rowskipB = (size_t)32 * ldb;
  const int woff = wave * 512;

  // prologue: issue batch(0) into buf 0 (stays in flight; waited in s=0)
#pragma unroll
  for (int i = 0; i < 4; i++)
    async16(Ag + i * rowskipA, &As[0][woff + i * 2048]);
#pragma unroll
  for (int i = 0; i < BN / 32; i++)
    async16(Bg + i * rowskipB, &Bs[0][woff + i * 2048]);

  const int nsteps = K >> 6;
  for (int s = 0; s < nsteps; ++s) {
    const int cur = s & 1;
    if (s + 1 < nsteps) {
      const int k0 = (s + 1) << 6;
      // issue batch(s+1) into buf cur^1 (read-clear by barrier #2 of s-1)
#pragma unroll
      for (int i = 0; i < 4; i++)
        async16(Ag + k0 + i * rowskipA, &As[cur ^ 1][woff + i * 2048]);
#pragma unroll
      for (int i = 0; i < BN / 32; i++)
        async16(Bg + k0 + i * rowskipB, &Bs[cur ^ 1][woff + i * 2048]);
      // wait batch(s) only; batch(s+1) (4+NT loads) stays outstanding
      asm volatile("s_waitcnt vmcnt(6)" ::: "memory");
    } else {
      asm volatile("s_waitcnt vmcnt(0)" ::: "memory");
    }
    __builtin_amdgcn_s_barrier();  // all waves' batch(s) landed in LDS
#pragma unroll
    for (int kk = 0; kk < 2; kk++) {
      short8 af[4], bf[NT];
#pragma unroll
      for (int mt = 0; mt < 4; mt++)
        af[mt] = *(const short8*)&As[cur][(wm + mt * 16 + lr) * 64 + (((kk * 4 + lg) ^ lr7) << 3)];
#pragma unroll
      for (int nt = 0; nt < NT; nt++)
        bf[nt] = *(const short8*)&Bs[cur][(wn + nt * 16 + lr) * 64 + (((kk * 4 + lg) ^ lr7) << 3)];
#pragma unroll
      for (int mt = 0; mt < 4; mt++)
#pragma unroll
        for (int nt = 0; nt < NT; nt++)
          acc[mt][nt] = mfma16(af[mt], bf[nt], acc[mt][nt]);
    }
    __builtin_amdgcn_s_barrier();  // readers of buf cur done before s+1's overwrite
  }
  gemm_epilogue<NT>(acc, Cv, ldc, bias, qscale, mode, tile_m, tile_n, wm, wn, lr, lg);
}

// down-projection: [4096,2048] x [1536,2048]^T -> [4096,1536] bf16.
// counted body BN=64: LDS 48KB -> 3 blocks/CU, grid 768 = exactly 3/CU.
__global__ __launch_bounds__(256)
void gemm_dn(const unsigned short* __restrict__ A,
             const unsigned short* __restrict__ B,
             unsigned short* __restrict__ C) {
  gemm_body_cnt<64>(A, 2048, B, 2048, C, 1536, nullptr, 1.0f, 2048, 0);
}

// output projection + bias -> fp32: counted body BN=64 (R6-validated).
__global__ __launch_bounds__(256)
void gemm_out(const unsigned short* __restrict__ A,
              const unsigned short* __restrict__ B,
              float* __restrict__ C, const float* __restrict__ bias) {
  gemm_body_cnt<64>(A, 2048, B, 2048, C, 2048, bias, 1.0f, 2048, 2);
}

// batched up-projection: z=0 -> Q (scaled), z=1 -> K, z=2 -> V^T permuted.
// REVERTED to drain128 (R8's cnt64 regressed +20us: K=512 = only 8 steps,
// BN=64 doubled A-traffic, 48KB LDS cut the 5+ blocks/CU occupancy that
// was already hiding latency via TLP).
__global__ __launch_bounds__(256)
void gemm_up(const unsigned short* __restrict__ cdown,
             const unsigned short* __restrict__ wup,
             unsigned short* __restrict__ qb,
             unsigned short* __restrict__ kb,
             unsigned short* __restrict__ vtb) {
  const int z = blockIdx.z;
  const unsigned short* A = cdown + z * 512;
  const unsigned short* B = wup + (size_t)z * 1048576;
  void* C; int mode; float qs = 1.0f;
  if (z == 0)      { C = qb;  mode = 3; qs = 0.12751744f; }  // (1/sqrt(128))*log2(e)
  else if (z == 1) { C = kb;  mode = 0; }
  else             { C = vtb; mode = 1; }
  gemm_body<128>(A, 1536, B, 512, C, 2048, nullptr, qs, 512, mode);
}

// ---------- flash attention (unshifted softmax, log2 domain) ----------
// 512 threads / 8 waves / 128 q-rows per block; 16 q-rows per wave.
// 2-tile pipeline: QK^T(t+1) and PV(t) issue back-to-back; P fragments in
// registers across the barrier. 74us = 924 TF (plain-HIP ladder level).
__global__ __launch_bounds__(512)
void attn(const unsigned short* __restrict__ q,
          const unsigned short* __restrict__ k,
          const unsigned short* __restrict__ vt,
          unsigned short* __restrict__ o) {
  __shared__ __align__(16) unsigned short Ks[2][64 * 128];
  __shared__ __align__(16) unsigned short Vs[2][128 * 64];
  __shared__ __align__(16) unsigned short Ps[8][16 * 64];

  const int tid  = threadIdx.x;
  const int wave = tid >> 6, lane = tid & 63;
  const int lr = lane & 15, lg = lane >> 4;
  // bijective XCD swizzle over 512 blocks: each XCD owns 4 bh x 16 q-tiles
  const int lin = blockIdx.x + (blockIdx.y << 4);
  const int xcd = lin & 7;
  const int lcl = lin >> 3;
  const int bh = (xcd << 2) | (lcl & 3);
  const int b = bh >> 4, h = bh & 15;
  const int q0 = (lcl >> 2) << 7;

  const size_t qrow = (size_t)(b * 2048 + q0 + wave * 16 + lr);
  short8 qf[4];
#pragma unroll
  for (int kk = 0; kk < 4; kk++)
    qf[kk] = *(const short8*)(q + qrow * 2048 + h * 128 + kk * 32 + lg * 8);

  f32x4 oacc[8];
  f32x4 lacc = (f32x4)0.0f;
#pragma unroll
  for (int n2 = 0; n2 < 8; n2++) oacc[n2] = (f32x4)0.0f;

  short8 ones;
#pragma unroll
  for (int j = 0; j < 8; j++) ones[j] = (short)0x3F80;  // bf16 1.0

  const unsigned short* kg = k  + (size_t)(b * 2048 + (tid >> 4)) * 2048 + h * 128
                               + ((((tid & 15) ^ (tid >> 4)) & 15) << 3);
  const unsigned short* vg = vt + (size_t)(bh * 128 + (tid >> 3)) * 2048
                               + (((tid & 7) ^ ((tid >> 3) & 7)) << 3);
  const int lr7 = lr & 7;

  // prologue staging: K(0)->Ks[0], V(0)->Vs[0], K(1)->Ks[1]
#pragma unroll
  for (int i = 0; i < 2; i++) {
    async16(kg + (size_t)(i * 32) * 2048, &Ks[0][i * 4096 + wave * 512]);
    async16(vg + (size_t)(i * 64) * 2048, &Vs[0][i * 4096 + wave * 512]);
    async16(kg + (size_t)(64 + i * 32) * 2048, &Ks[1][i * 4096 + wave * 512]);
  }
  __syncthreads();  // vmcnt(0): K0,V0,K1 resident

  short8 pfA, pfB;
  {
    // QK^T(0)
    f32x4 sv[4];
#pragma unroll
    for (int nt = 0; nt < 4; nt++) sv[nt] = (f32x4)0.0f;
#pragma unroll
    for (int nt = 0; nt < 4; nt++) {
#pragma unroll
      for (int kk = 0; kk < 4; kk++) {
        short8 kf = *(const short8*)&Ks[0][(nt * 16 + lr) * 128 + (((kk * 4 + lg) ^ lr) << 3)];
        sv[nt] = mfma16(qf[kk], kf, sv[nt]);
      }
    }
    // exp(0) -> Ps -> pf regs
#pragma unroll
    for (int r = 0; r < 4; r++) {
      float p0 = exp2r(sv[0][r]);
      float p1 = exp2r(sv[1][r]);
      float p2 = exp2r(sv[2][r]);
      float p3 = exp2r(sv[3][r]);
      uint2 pk; pk.x = pkbf(p0, p1); pk.y = pkbf(p2, p3);
      int row = lg * 4 + r;
      *(uint2*)&Ps[wave][row * 64 + ((lr ^ (lg << 2)) << 2)] = pk;
    }
    pfA = *(const short8*)&Ps[wave][lr * 64 + (((lg * 2) ^ ((lr >> 2) << 2)) << 2)];
    pfB = *(const short8*)&Ps[wave][lr * 64 + (((8 + lg * 2) ^ ((lr >> 2) << 2)) << 2)];
  }
  __syncthreads();  // all waves done reading Ks[0] before iter0 overwrites it

  for (int t = 0; t < 31; ++t) {
    const int buf = t & 1;
    // stage K(t+2) into Ks[buf] (last read by QKT(t) in iter t-1)
    if (t < 30) {
#pragma unroll
      for (int i = 0; i < 2; i++)
        async16(kg + (size_t)((t + 2) * 64 + i * 32) * 2048, &Ks[buf][i * 4096 + wave * 512]);
    }
    // stage V(t+1) into Vs[buf^1] (last read by PV(t-1) in iter t-1)
#pragma unroll
    for (int i = 0; i < 2; i++)
      async16(vg + (t + 1) * 64 + (size_t)(i * 64) * 2048, &Vs[buf ^ 1][i * 4096 + wave * 512]);

    const unsigned short* KsN = Ks[buf ^ 1];
    const unsigned short* VsB = Vs[buf];

    __builtin_amdgcn_s_setprio(1);
    // QK^T(t+1) — independent of PV(t)
    f32x4 sv[4];
#pragma unroll
    for (int nt = 0; nt < 4; nt++) sv[nt] = (f32x4)0.0f;
#pragma unroll
    for (int nt = 0; nt < 4; nt++) {
#pragma unroll
      for (int kk = 0; kk < 4; kk++) {
        short8 kf = *(const short8*)&KsN[(nt * 16 + lr) * 128 + (((kk * 4 + lg) ^ lr) << 3)];
        sv[nt] = mfma16(qf[kk], kf, sv[nt]);
      }
    }

    // PV(t) from register-held P fragments + Vs[buf]
    lacc = mfma16(pfA, ones, lacc);
#pragma unroll
    for (int n2 = 0; n2 < 8; n2++) {
      short8 vf = *(const short8*)&VsB[(n2 * 16 + lr) * 64 + ((lg ^ lr7) << 3)];
      oacc[n2] = mfma16(pfA, vf, oacc[n2]);
    }
    lacc = mfma16(pfB, ones, lacc);
#pragma unroll
    for (int n2 = 0; n2 < 8; n2++) {
      short8 vf = *(const short8*)&VsB[(n2 * 16 + lr) * 64 + (((4 + lg) ^ lr7) << 3)];
      oacc[n2] = mfma16(pfB, vf, oacc[n2]);
    }
    __builtin_amdgcn_s_setprio(0);

    // exp(t+1) -> Ps -> pf regs
#pragma unroll
    for (int r = 0; r < 4; r++) {
      float p0 = exp2r(sv[0][r]);
      float p1 = exp2r(sv[1][r]);
      float p2 = exp2r(sv[2][r]);
      float p3 = exp2r(sv[3][r]);
      uint2 pk; pk.x = pkbf(p0, p1); pk.y = pkbf(p2, p3);
      int row = lg * 4 + r;
      *(uint2*)&Ps[wave][row * 64 + ((lr ^ (lg << 2)) << 2)] = pk;
    }
    pfA = *(const short8*)&Ps[wave][lr * 64 + (((lg * 2) ^ ((lr >> 2) << 2)) << 2)];
    pfB = *(const short8*)&Ps[wave][lr * 64 + (((8 + lg * 2) ^ ((lr >> 2) << 2)) << 2)];

    __syncthreads();
  }

  // final PV(31) from Vs[1]
  {
    const unsigned short* VsB = Vs[1];
    __builtin_amdgcn_s_setprio(1);
    lacc = mfma16(pfA, ones, lacc);
#pragma unroll
    for (int n2 = 0; n2 < 8; n2++) {
      short8 vf = *(const short8*)&VsB[(n2 * 16 + lr) * 64 + ((lg ^ lr7) << 3)];
      oacc[n2] = mfma16(pfA, vf, oacc[n2]);
    }
    lacc = mfma16(pfB, ones, lacc);
#pragma unroll
    for (int n2 = 0; n2 < 8; n2++) {
      short8 vf = *(const short8*)&VsB[(n2 * 16 + lr) * 64 + (((4 + lg) ^ lr7) << 3)];
      oacc[n2] = mfma16(pfB, vf, oacc[n2]);
    }
    __builtin_amdgcn_s_setprio(0);
  }

  // epilogue: l in C-layout aligned with oacc rows
  f32x4 inv;
#pragma unroll
  for (int r = 0; r < 4; r++) inv[r] = 1.0f / lacc[r];
#pragma unroll
  for (int n2 = 0; n2 < 8; n2++)
#pragma unroll
    for (int r = 0; r < 4; r++) {
      size_t row = (size_t)(b * 2048 + q0 + wave * 16 + lg * 4 + r);
      o[row * 2048 + h * 128 + n2 * 16 + lr] = f2bf(oacc[n2][r] * inv[r]);
    }
}

// ---------- host ----------
extern "C" void kernel_launch(void* const* d_in, const int* in_sizes, int n_in,
                              void* d_out, int out_size, void* d_ws, size_t ws_size,
                              hipStream_t stream) {
  const float* x    = (const float*)d_in[0];
  const float* wq_a = (const float*)d_in[1];
  const float* wq_b = (const float*)d_in[2];
  const float* wk_a = (const float*)d_in[3];
  const float* wk_b = (const float*)d_in[4];
  const float* wv_a = (const float*)d_in[5];
  const float* wv_b = (const float*)d_in[6];
  const float* wo_w = (const float*)d_in[7];
  const float* wo_b = (const float*)d_in[8];
  float* out = (float*)d_out;

  unsigned short* ws = (unsigned short*)d_ws;
  unsigned short* xb    = ws;
  unsigned short* wdown = ws + 8388608;    // [1536][2048]
  unsigned short* wupb  = ws + 11534336;   // [3][2048][512]
  unsigned short* wow   = ws + 14680064;   // [2048][2048]
  unsigned short* cdown = ws + 18874368;   // [4096][1536]
  unsigned short* qb    = ws + 25165824;   // [4096][2048]
  unsigned short* kb    = ws + 33554432;
  unsigned short* vtb   = ws + 41943040;
  unsigned short* ao    = ws + 50331648;

  cast_all<<<dim3(2048), dim3(256), 0, stream>>>(x, wq_a, wq_b, wk_a, wk_b, wv_a, wv_b, wo_w, ws);

  // fused down-projection: [4096,2048] x [1536,2048]^T -> [4096,1536]
  gemm_dn<<<dim3(24, 32), dim3(256), 0, stream>>>(xb, wdown, cdown);

  // batched up-projections (Q scaled, K plain, V transposed+permuted)
  gemm_up<<<dim3(16, 32, 3), dim3(256), 0, stream>>>(cdown, wupb, qb, kb, vtb);

  attn<<<dim3(16, 32), dim3(512), 0, stream>>>(qb, kb, vtb, ao);

  // output projection + bias -> fp32 (counted-vmcnt BN=64, R6-validated)
  gemm_out<<<dim3(32, 32), dim3(256), 0, stream>>>(ao, wow, out, wo_b);
}

// Round 10
// 322.493 us; speedup vs baseline: 1.0907x; 1.0393x over previous
//
#include <hip/hip_runtime.h>

// ---------- types ----------
typedef __attribute__((ext_vector_type(8))) short short8;
typedef __attribute__((ext_vector_type(4))) float f32x4;
typedef __attribute__((ext_vector_type(4))) float float4v;
typedef __attribute__((ext_vector_type(4))) unsigned short us4;

__device__ __forceinline__ unsigned short f2bf(float f) {
  union { float f; unsigned int u; } c; c.f = f;
  unsigned int u = c.u;
  u += 0x7fffu + ((u >> 16) & 1u);
  return (unsigned short)(u >> 16);
}

__device__ __forceinline__ unsigned int pkbf(float a, float b) {
  unsigned int r;
  asm("v_cvt_pk_bf16_f32 %0, %1, %2" : "=v"(r) : "v"(a), "v"(b));
  return r;
}

// 2^x via compiler-known TRANS op (hazard nops handled by backend).
__device__ __forceinline__ float exp2r(float x) {
#if __has_builtin(__builtin_amdgcn_exp2f)
  return __builtin_amdgcn_exp2f(x);
#else
  return exp2f(x);
#endif
}

__device__ __forceinline__ void async16(const void* g, void* l) {
  __builtin_amdgcn_global_load_lds(
      (const __attribute__((address_space(1))) unsigned int*)g,
      (__attribute__((address_space(3))) unsigned int*)l, 16, 0, 0);
}

__device__ __forceinline__ f32x4 mfma16(short8 a, short8 b, f32x4 c) {
  return __builtin_amdgcn_mfma_f32_16x16x32_bf16(a, b, c, 0, 0, 0);
}

// ---------- fused fp32 -> bf16 cast, reordered for fused GEMMs ----------
__global__ void cast_all(const float* __restrict__ x,
                         const float* __restrict__ wqa, const float* __restrict__ wqb,
                         const float* __restrict__ wka, const float* __restrict__ wkb,
                         const float* __restrict__ wva, const float* __restrict__ wvb,
                         const float* __restrict__ wow,
                         unsigned short* __restrict__ out) {
  int c = blockIdx.x * 256 + threadIdx.x;
  const int stride = gridDim.x * 256;
  for (; c < 4718592; c += stride) {
    int i = c << 2;
    const float* src; int off;
    if (i < 8388608)       { src = x;   off = 0; }
    else if (i < 9437184)  { src = wqa; off = 8388608; }
    else if (i < 10485760) { src = wka; off = 9437184; }
    else if (i < 11534336) { src = wva; off = 10485760; }
    else if (i < 12582912) { src = wqb; off = 11534336; }
    else if (i < 13631488) { src = wkb; off = 12582912; }
    else if (i < 14680064) { src = wvb; off = 13631488; }
    else                   { src = wow; off = 14680064; }
    float4v v = *(const float4v*)(src + (i - off));
    us4 r;
    r[0] = f2bf(v[0]); r[1] = f2bf(v[1]); r[2] = f2bf(v[2]); r[3] = f2bf(v[3]);
    *(us4*)(out + i) = r;
  }
}

// ---------- GEMM epilogue (shared; modes 0/2/3) ----------
// modes: 0 bf16 | 2 fp32+bias | 3 bf16*qscale (mode 1 handled in-body)
template <int NT>
__device__ __forceinline__ void gemm_epilogue(
    f32x4 (&acc)[4][NT], void* __restrict__ Cv, int ldc,
    const float* __restrict__ bias, float qscale, int mode,
    int tile_m, int tile_n, int wm, int wn, int lr, int lg) {
#pragma unroll
  for (int mt = 0; mt < 4; mt++) {
#pragma unroll
    for (int nt = 0; nt < NT; nt++) {
#pragma unroll
      for (int r = 0; r < 4; r++) {
        int row = tile_m + wm + mt * 16 + lg * 4 + r;
        int col = tile_n + wn + nt * 16 + lr;
        float v = acc[mt][nt][r];
        if (mode == 0) {
          ((unsigned short*)Cv)[(size_t)row * ldc + col] = f2bf(v);
        } else if (mode == 3) {
          ((unsigned short*)Cv)[(size_t)row * ldc + col] = f2bf(v * qscale);
        } else {
          ((float*)Cv)[(size_t)row * ldc + col] = v + bias[col];
        }
      }
    }
  }
}

// ---------- GEMM body (2-barrier, single-buffer drain) — gemm_up only ----
// For short-K / occupancy-rich shapes (K=512, 32KB LDS -> 5 blocks/CU):
// wave-level TLP already hides staging latency (m114 regime); R8 showed
// the counted pipeline REGRESSES here (+20us).
// mode 1 (V^T key-permuted) uses an LDS-transpose epilogue: the naive
// per-element store scatters 64 lanes across 4KB-stride lines (64 lines
// per store instr, ~4096 TA transactions/wave). Transposing through the
// (reused) As/Bs LDS emits 8B stores with 16 lanes contiguous per d-row
// (~8 lines/instr). Same bits to same addresses -> bit-exact.
template <int BN>
__device__ __forceinline__ void gemm_body(
    const unsigned short* __restrict__ A, int lda,
    const unsigned short* __restrict__ B, int ldb,
    void* __restrict__ Cv, int ldc,
    const float* __restrict__ bias, float qscale, int K, int mode) {
  constexpr int NT = BN / 32;
  // unified LDS: As|Bs during the K-loop; reused as the 64x132 bf16
  // transpose buffer (8448 shorts <= 16384) for the mode-1 epilogue.
  __shared__ __align__(16) unsigned short smem[8192 + BN * 64];
  unsigned short* As = smem;
  unsigned short* Bs = smem + 8192;
  const int tid  = threadIdx.x;
  const int wave = tid >> 6, lane = tid & 63;
  const int lr = lane & 15, lg = lane >> 4;
  const int lr7 = lr & 7;
  const int tile_m = blockIdx.y << 7;
  const int tile_n = blockIdx.x * BN;
  const int wm = (wave & 1) << 6;
  const int wn = (wave >> 1) * (BN / 2);

  f32x4 acc[4][NT];
#pragma unroll
  for (int i = 0; i < 4; i++)
#pragma unroll
    for (int j = 0; j < NT; j++) acc[i][j] = (f32x4)0.0f;

  const int srow = tid >> 3;
  const int cg = ((tid & 7) ^ (srow & 7)) << 3;
  const unsigned short* Ag = A + (size_t)(tile_m + srow) * lda + cg;
  const unsigned short* Bg = B + (size_t)(tile_n + srow) * ldb + cg;
  const size_t rowskipA = (size_t)32 * lda;
  const size_t rowskipB = (size_t)32 * ldb;
  unsigned short* AsW = As + wave * 512;
  unsigned short* BsW = Bs + wave * 512;

  for (int k0 = 0; k0 < K; k0 += 64) {
#pragma unroll
    for (int i = 0; i < 4; i++)
      async16(Ag + k0 + i * rowskipA, AsW + i * 2048);
#pragma unroll
    for (int i = 0; i < BN / 32; i++)
      async16(Bg + k0 + i * rowskipB, BsW + i * 2048);
    __syncthreads();
#pragma unroll
    for (int kk = 0; kk < 2; kk++) {
      short8 af[4], bf[NT];
#pragma unroll
      for (int mt = 0; mt < 4; mt++)
        af[mt] = *(const short8*)&As[(wm + mt * 16 + lr) * 64 + (((kk * 4 + lg) ^ lr7) << 3)];
#pragma unroll
      for (int nt = 0; nt < NT; nt++)
        bf[nt] = *(const short8*)&Bs[(wn + nt * 16 + lr) * 64 + (((kk * 4 + lg) ^ lr7) << 3)];
#pragma unroll
      for (int mt = 0; mt < 4; mt++)
#pragma unroll
        for (int nt = 0; nt < NT; nt++)
          acc[mt][nt] = mfma16(af[mt], bf[nt], acc[mt][nt]);
    }
    __syncthreads();
  }

  if (mode == 1) {
    // V^T permuted epilogue via LDS transpose (BN=128 only; two e-halves
    // of 64 rows each so the buffer fits in the K-loop's 32KB LDS).
    // Permutation closed form: t_loc = wm + mt*16 + lg*4 + r maps to
    // tp_local = wm + lg*16 + r*4 + mt  (= (t&64) | perm(t&63)).
    unsigned short* trans = smem;          // [64][132] padded (4-way wr, 2-way rd)
    const int b2048 = (tile_m >> 11) << 11;
    const int tbase = tile_m & 2047;
    const int tpc = (tid & 15) << 3;       // 8-elem tp chunk base
#pragma unroll
    for (int half = 0; half < 2; ++half) {
      if (wn == half * 64) {
#pragma unroll
        for (int mt = 0; mt < 4; mt++)
#pragma unroll
          for (int nt = 0; nt < NT; nt++)
#pragma unroll
            for (int r = 0; r < 4; r++)
              trans[(nt * 16 + lr) * 132 + wm + lg * 16 + r * 4 + mt] =
                  f2bf(acc[mt][nt][r]);
      }
      __syncthreads();
#pragma unroll
      for (int j = 0; j < 4; j++) {
        const int dl = (tid >> 4) + j * 16;       // d-row within this half
        uint2 v0 = *(const uint2*)&trans[dl * 132 + tpc];
        uint2 v1 = *(const uint2*)&trans[dl * 132 + tpc + 4];
        size_t o = (size_t)(b2048 + tile_n + half * 64 + dl) * 2048 + tbase + tpc;
        *(uint2*)&((unsigned short*)Cv)[o]     = v0;
        *(uint2*)&((unsigned short*)Cv)[o + 4] = v1;
      }
      __syncthreads();
    }
    return;
  }
  gemm_epilogue<NT>(acc, Cv, ldc, bias, qscale, mode, tile_m, tile_n, wm, wn, lr, lg);
}

// ---------- GEMM body, counted-vmcnt pipeline (T4, validated R6) ----------
// For long-K / occupancy-thin shapes (K=2048, 3 blocks/CU): prefetch for
// step s+1 stays IN FLIGHT across the barriers: issue batch(s+1) ->
// s_waitcnt vmcnt(6) (waits only batch s; never 0 in-loop) -> raw barrier
// -> compute(s) -> raw barrier. R6 A/B: -8us vs drain on out-proj.
// R7: BN=128 (2 blocks/CU) ~4us worse than BN=64 -> cnt64 is the config.
template <int BN>
__device__ __forceinline__ void gemm_body_cnt(
    const unsigned short* __restrict__ A, int lda,
    const unsigned short* __restrict__ B, int ldb,
    void* __restrict__ Cv, int ldc,
    const float* __restrict__ bias, float qscale, int K, int mode) {
  constexpr int NT = BN / 32;
  __shared__ __align__(16) unsigned short As[2][128 * 64];
  __shared__ __align__(16) unsigned short Bs[2][BN * 64];
  const int tid  = threadIdx.x;
  const int wave = tid >> 6, lane = tid & 63;
  const int lr = lane & 15, lg = lane >> 4;
  const int lr7 = lr & 7;
  const int tile_m = blockIdx.y << 7;
  const int tile_n = blockIdx.x * BN;
  const int wm = (wave & 1) << 6;
  const int wn = (wave >> 1) * (BN / 2);

  f32x4 acc[4][NT];
#pragma unroll
  for (int i = 0; i < 4; i++)
#pragma unroll
    for (int j = 0; j < NT; j++) acc[i][j] = (f32x4)0.0f;

  const int srow = tid >> 3;
  const int cg = ((tid & 7) ^ (srow & 7)) << 3;
  const unsigned short* Ag = A + (size_t)(tile_m + srow) * lda + cg;
  const unsigned short* Bg = B + (size_t)(tile_n + srow) * ldb + cg;
  const size_t rowskipA = (size_t)32 * lda;
  const size_t rowskipB = (size_t)32 * ldb;
  const int woff = wave * 512;

  // prologue: issue batch(0) into buf 0 (stays in flight; waited in s=0)
#pragma unroll
  for (int i = 0; i < 4; i++)
    async16(Ag + i * rowskipA, &As[0][woff + i * 2048]);
#pragma unroll
  for (int i = 0; i < BN / 32; i++)
    async16(Bg + i * rowskipB, &Bs[0][woff + i * 2048]);

  const int nsteps = K >> 6;
  for (int s = 0; s < nsteps; ++s) {
    const int cur = s & 1;
    if (s + 1 < nsteps) {
      const int k0 = (s + 1) << 6;
      // issue batch(s+1) into buf cur^1 (read-clear by barrier #2 of s-1)
#pragma unroll
      for (int i = 0; i < 4; i++)
        async16(Ag + k0 + i * rowskipA, &As[cur ^ 1][woff + i * 2048]);
#pragma unroll
      for (int i = 0; i < BN / 32; i++)
        async16(Bg + k0 + i * rowskipB, &Bs[cur ^ 1][woff + i * 2048]);
      // wait batch(s) only; batch(s+1) (4+NT loads) stays outstanding
      asm volatile("s_waitcnt vmcnt(6)" ::: "memory");
    } else {
      asm volatile("s_waitcnt vmcnt(0)" ::: "memory");
    }
    __builtin_amdgcn_s_barrier();  // all waves' batch(s) landed in LDS
#pragma unroll
    for (int kk = 0; kk < 2; kk++) {
      short8 af[4], bf[NT];
#pragma unroll
      for (int mt = 0; mt < 4; mt++)
        af[mt] = *(const short8*)&As[cur][(wm + mt * 16 + lr) * 64 + (((kk * 4 + lg) ^ lr7) << 3)];
#pragma unroll
      for (int nt = 0; nt < NT; nt++)
        bf[nt] = *(const short8*)&Bs[cur][(wn + nt * 16 + lr) * 64 + (((kk * 4 + lg) ^ lr7) << 3)];
#pragma unroll
      for (int mt = 0; mt < 4; mt++)
#pragma unroll
        for (int nt = 0; nt < NT; nt++)
          acc[mt][nt] = mfma16(af[mt], bf[nt], acc[mt][nt]);
    }
    __builtin_amdgcn_s_barrier();  // readers of buf cur done before s+1's overwrite
  }
  gemm_epilogue<NT>(acc, Cv, ldc, bias, qscale, mode, tile_m, tile_n, wm, wn, lr, lg);
}

// down-projection: [4096,2048] x [1536,2048]^T -> [4096,1536] bf16.
// counted body BN=64: LDS 48KB -> 3 blocks/CU, grid 768 = exactly 3/CU.
__global__ __launch_bounds__(256)
void gemm_dn(const unsigned short* __restrict__ A,
             const unsigned short* __restrict__ B,
             unsigned short* __restrict__ C) {
  gemm_body_cnt<64>(A, 2048, B, 2048, C, 1536, nullptr, 1.0f, 2048, 0);
}

// output projection + bias -> fp32: counted body BN=64 (R6-validated).
__global__ __launch_bounds__(256)
void gemm_out(const unsigned short* __restrict__ A,
              const unsigned short* __restrict__ B,
              float* __restrict__ C, const float* __restrict__ bias) {
  gemm_body_cnt<64>(A, 2048, B, 2048, C, 2048, bias, 1.0f, 2048, 2);
}

// batched up-projection: z=0 -> Q (scaled), z=1 -> K, z=2 -> V^T permuted.
// drain128 (R8's cnt64 regressed +20us here); mode-1 now uses the
// LDS-transpose coalesced epilogue.
__global__ __launch_bounds__(256)
void gemm_up(const unsigned short* __restrict__ cdown,
             const unsigned short* __restrict__ wup,
             unsigned short* __restrict__ qb,
             unsigned short* __restrict__ kb,
             unsigned short* __restrict__ vtb) {
  const int z = blockIdx.z;
  const unsigned short* A = cdown + z * 512;
  const unsigned short* B = wup + (size_t)z * 1048576;
  void* C; int mode; float qs = 1.0f;
  if (z == 0)      { C = qb;  mode = 3; qs = 0.12751744f; }  // (1/sqrt(128))*log2(e)
  else if (z == 1) { C = kb;  mode = 0; }
  else             { C = vtb; mode = 1; }
  gemm_body<128>(A, 1536, B, 512, C, 2048, nullptr, qs, 512, mode);
}

// ---------- flash attention (unshifted softmax, log2 domain) ----------
// 512 threads / 8 waves / 128 q-rows per block; 16 q-rows per wave.
// 2-tile pipeline: QK^T(t+1) and PV(t) issue back-to-back; P fragments in
// registers across the barrier. 74us = 924 TF (plain-HIP ladder level).
__global__ __launch_bounds__(512)
void attn(const unsigned short* __restrict__ q,
          const unsigned short* __restrict__ k,
          const unsigned short* __restrict__ vt,
          unsigned short* __restrict__ o) {
  __shared__ __align__(16) unsigned short Ks[2][64 * 128];
  __shared__ __align__(16) unsigned short Vs[2][128 * 64];
  __shared__ __align__(16) unsigned short Ps[8][16 * 64];

  const int tid  = threadIdx.x;
  const int wave = tid >> 6, lane = tid & 63;
  const int lr = lane & 15, lg = lane >> 4;
  // bijective XCD swizzle over 512 blocks: each XCD owns 4 bh x 16 q-tiles
  const int lin = blockIdx.x + (blockIdx.y << 4);
  const int xcd = lin & 7;
  const int lcl = lin >> 3;
  const int bh = (xcd << 2) | (lcl & 3);
  const int b = bh >> 4, h = bh & 15;
  const int q0 = (lcl >> 2) << 7;

  const size_t qrow = (size_t)(b * 2048 + q0 + wave * 16 + lr);
  short8 qf[4];
#pragma unroll
  for (int kk = 0; kk < 4; kk++)
    qf[kk] = *(const short8*)(q + qrow * 2048 + h * 128 + kk * 32 + lg * 8);

  f32x4 oacc[8];
  f32x4 lacc = (f32x4)0.0f;
#pragma unroll
  for (int n2 = 0; n2 < 8; n2++) oacc[n2] = (f32x4)0.0f;

  short8 ones;
#pragma unroll
  for (int j = 0; j < 8; j++) ones[j] = (short)0x3F80;  // bf16 1.0

  const unsigned short* kg = k  + (size_t)(b * 2048 + (tid >> 4)) * 2048 + h * 128
                               + ((((tid & 15) ^ (tid >> 4)) & 15) << 3);
  const unsigned short* vg = vt + (size_t)(bh * 128 + (tid >> 3)) * 2048
                               + (((tid & 7) ^ ((tid >> 3) & 7)) << 3);
  const int lr7 = lr & 7;

  // prologue staging: K(0)->Ks[0], V(0)->Vs[0], K(1)->Ks[1]
#pragma unroll
  for (int i = 0; i < 2; i++) {
    async16(kg + (size_t)(i * 32) * 2048, &Ks[0][i * 4096 + wave * 512]);
    async16(vg + (size_t)(i * 64) * 2048, &Vs[0][i * 4096 + wave * 512]);
    async16(kg + (size_t)(64 + i * 32) * 2048, &Ks[1][i * 4096 + wave * 512]);
  }
  __syncthreads();  // vmcnt(0): K0,V0,K1 resident

  short8 pfA, pfB;
  {
    // QK^T(0)
    f32x4 sv[4];
#pragma unroll
    for (int nt = 0; nt < 4; nt++) sv[nt] = (f32x4)0.0f;
#pragma unroll
    for (int nt = 0; nt < 4; nt++) {
#pragma unroll
      for (int kk = 0; kk < 4; kk++) {
        short8 kf = *(const short8*)&Ks[0][(nt * 16 + lr) * 128 + (((kk * 4 + lg) ^ lr) << 3)];
        sv[nt] = mfma16(qf[kk], kf, sv[nt]);
      }
    }
    // exp(0) -> Ps -> pf regs
#pragma unroll
    for (int r = 0; r < 4; r++) {
      float p0 = exp2r(sv[0][r]);
      float p1 = exp2r(sv[1][r]);
      float p2 = exp2r(sv[2][r]);
      float p3 = exp2r(sv[3][r]);
      uint2 pk; pk.x = pkbf(p0, p1); pk.y = pkbf(p2, p3);
      int row = lg * 4 + r;
      *(uint2*)&Ps[wave][row * 64 + ((lr ^ (lg << 2)) << 2)] = pk;
    }
    pfA = *(const short8*)&Ps[wave][lr * 64 + (((lg * 2) ^ ((lr >> 2) << 2)) << 2)];
    pfB = *(const short8*)&Ps[wave][lr * 64 + (((8 + lg * 2) ^ ((lr >> 2) << 2)) << 2)];
  }
  __syncthreads();  // all waves done reading Ks[0] before iter0 overwrites it

  for (int t = 0; t < 31; ++t) {
    const int buf = t & 1;
    // stage K(t+2) into Ks[buf] (last read by QKT(t) in iter t-1)
    if (t < 30) {
#pragma unroll
      for (int i = 0; i < 2; i++)
        async16(kg + (size_t)((t + 2) * 64 + i * 32) * 2048, &Ks[buf][i * 4096 + wave * 512]);
    }
    // stage V(t+1) into Vs[buf^1] (last read by PV(t-1) in iter t-1)
#pragma unroll
    for (int i = 0; i < 2; i++)
      async16(vg + (t + 1) * 64 + (size_t)(i * 64) * 2048, &Vs[buf ^ 1][i * 4096 + wave * 512]);

    const unsigned short* KsN = Ks[buf ^ 1];
    const unsigned short* VsB = Vs[buf];

    __builtin_amdgcn_s_setprio(1);
    // QK^T(t+1) — independent of PV(t)
    f32x4 sv[4];
#pragma unroll
    for (int nt = 0; nt < 4; nt++) sv[nt] = (f32x4)0.0f;
#pragma unroll
    for (int nt = 0; nt < 4; nt++) {
#pragma unroll
      for (int kk = 0; kk < 4; kk++) {
        short8 kf = *(const short8*)&KsN[(nt * 16 + lr) * 128 + (((kk * 4 + lg) ^ lr) << 3)];
        sv[nt] = mfma16(qf[kk], kf, sv[nt]);
      }
    }

    // PV(t) from register-held P fragments + Vs[buf]
    lacc = mfma16(pfA, ones, lacc);
#pragma unroll
    for (int n2 = 0; n2 < 8; n2++) {
      short8 vf = *(const short8*)&VsB[(n2 * 16 + lr) * 64 + ((lg ^ lr7) << 3)];
      oacc[n2] = mfma16(pfA, vf, oacc[n2]);
    }
    lacc = mfma16(pfB, ones, lacc);
#pragma unroll
    for (int n2 = 0; n2 < 8; n2++) {
      short8 vf = *(const short8*)&VsB[(n2 * 16 + lr) * 64 + (((4 + lg) ^ lr7) << 3)];
      oacc[n2] = mfma16(pfB, vf, oacc[n2]);
    }
    __builtin_amdgcn_s_setprio(0);

    // exp(t+1) -> Ps -> pf regs
#pragma unroll
    for (int r = 0; r < 4; r++) {
      float p0 = exp2r(sv[0][r]);
      float p1 = exp2r(sv[1][r]);
      float p2 = exp2r(sv[2][r]);
      float p3 = exp2r(sv[3][r]);
      uint2 pk; pk.x = pkbf(p0, p1); pk.y = pkbf(p2, p3);
      int row = lg * 4 + r;
      *(uint2*)&Ps[wave][row * 64 + ((lr ^ (lg << 2)) << 2)] = pk;
    }
    pfA = *(const short8*)&Ps[wave][lr * 64 + (((lg * 2) ^ ((lr >> 2) << 2)) << 2)];
    pfB = *(const short8*)&Ps[wave][lr * 64 + (((8 + lg * 2) ^ ((lr >> 2) << 2)) << 2)];

    __syncthreads();
  }

  // final PV(31) from Vs[1]
  {
    const unsigned short* VsB = Vs[1];
    __builtin_amdgcn_s_setprio(1);
    lacc = mfma16(pfA, ones, lacc);
#pragma unroll
    for (int n2 = 0; n2 < 8; n2++) {
      short8 vf = *(const short8*)&VsB[(n2 * 16 + lr) * 64 + ((lg ^ lr7) << 3)];
      oacc[n2] = mfma16(pfA, vf, oacc[n2]);
    }
    lacc = mfma16(pfB, ones, lacc);
#pragma unroll
    for (int n2 = 0; n2 < 8; n2++) {
      short8 vf = *(const short8*)&VsB[(n2 * 16 + lr) * 64 + (((4 + lg) ^ lr7) << 3)];
      oacc[n2] = mfma16(pfB, vf, oacc[n2]);
    }
    __builtin_amdgcn_s_setprio(0);
  }

  // epilogue: l in C-layout aligned with oacc rows
  f32x4 inv;
#pragma unroll
  for (int r = 0; r < 4; r++) inv[r] = 1.0f / lacc[r];
#pragma unroll
  for (int n2 = 0; n2 < 8; n2++)
#pragma unroll
    for (int r = 0; r < 4; r++) {
      size_t row = (size_t)(b * 2048 + q0 + wave * 16 + lg * 4 + r);
      o[row * 2048 + h * 128 + n2 * 16 + lr] = f2bf(oacc[n2][r] * inv[r]);
    }
}

// ---------- host ----------
extern "C" void kernel_launch(void* const* d_in, const int* in_sizes, int n_in,
                              void* d_out, int out_size, void* d_ws, size_t ws_size,
                              hipStream_t stream) {
  const float* x    = (const float*)d_in[0];
  const float* wq_a = (const float*)d_in[1];
  const float* wq_b = (const float*)d_in[2];
  const float* wk_a = (const float*)d_in[3];
  const float* wk_b = (const float*)d_in[4];
  const float* wv_a = (const float*)d_in[5];
  const float* wv_b = (const float*)d_in[6];
  const float* wo_w = (const float*)d_in[7];
  const float* wo_b = (const float*)d_in[8];
  float* out = (float*)d_out;

  unsigned short* ws = (unsigned short*)d_ws;
  unsigned short* xb    = ws;
  unsigned short* wdown = ws + 8388608;    // [1536][2048]
  unsigned short* wupb  = ws + 11534336;   // [3][2048][512]
  unsigned short* wow   = ws + 14680064;   // [2048][2048]
  unsigned short* cdown = ws + 18874368;   // [4096][1536]
  unsigned short* qb    = ws + 25165824;   // [4096][2048]
  unsigned short* kb    = ws + 33554432;
  unsigned short* vtb   = ws + 41943040;
  unsigned short* ao    = ws + 50331648;

  cast_all<<<dim3(2048), dim3(256), 0, stream>>>(x, wq_a, wq_b, wk_a, wk_b, wv_a, wv_b, wo_w, ws);

  // fused down-projection: [4096,2048] x [1536,2048]^T -> [4096,1536]
  gemm_dn<<<dim3(24, 32), dim3(256), 0, stream>>>(xb, wdown, cdown);

  // batched up-projections (Q scaled, K plain, V transposed+permuted)
  gemm_up<<<dim3(16, 32, 3), dim3(256), 0, stream>>>(cdown, wupb, qb, kb, vtb);

  attn<<<dim3(16, 32), dim3(512), 0, stream>>>(qb, kb, vtb, ao);

  // output projection + bias -> fp32 (counted-vmcnt BN=64, R6-validated)
  gemm_out<<<dim3(32, 32), dim3(256), 0, stream>>>(ao, wow, out, wo_b);
}